// Round 4
// baseline (1091.488 us; speedup 1.0000x reference)
//
#include <hip/hip_runtime.h>
#include <cstdint>

// FNet block on MI355X.
//   attn = Re(FFT2(x)) via bf16 MFMA matmuls + real-input quadrant symmetry:
//     GEMM1: T[r][0:512]=Tc, T[r][512:1024]=Ts   (M=32768, N=1024, K=768)
//     transpose_T: BtU[b][d][s]=Tc[s,d], BtV[b][d][s]=Ts[s,d]
//     GEMM_uv (fused, z=0..15): u[z][k][d] (cos) / v[z][k][d] (sin), M=2304(pad),N=512,K=4096
//     combine: attn[k,d]=u-v; [k,768-d]=u+v; [4096-k,d]=u+v; [4096-k,768-d]=u-v
//   LN1 -> out1 (bf16)
//   GEMM3: H = gelu(out1 @ W1 + b1)       (M=32768, N=3072, K=768)
//   GEMM4: y2 = H @ W2 + b2 + out1        (M=32768, N=768, K=3072)
//   LN2 in-place on d_out.
// GEMM core: 256x256 tile, BK=64, 8 waves, LDS 128 KiB double-buffer,
// global_load_lds(16B) staging with 2-deep prefetch and counted vmcnt(8)
// (never drained to 0 in the main loop), T2 LDS XOR-swizzle, setprio around
// MFMA clusters. Raw s_barrier + sched_barrier(0) fences (no __syncthreads drain).

typedef __attribute__((ext_vector_type(8))) short short8;
typedef __attribute__((ext_vector_type(4))) float f32x4;

__device__ __forceinline__ unsigned short f2b(float f) {
  union { float f; uint32_t u; } c; c.f = f;
  uint32_t u = c.u;
  u += 0x7FFFu + ((u >> 16) & 1u);   // round-to-nearest-even
  return (unsigned short)(u >> 16);
}
__device__ __forceinline__ float b2f(unsigned short h) {
  union { uint32_t u; float f; } c; c.u = ((uint32_t)h) << 16;
  return c.f;
}

// ---------------------------------------------------------------------------
// Fill / convert kernels (unchanged from verified round-3 kernel)
// ---------------------------------------------------------------------------

__global__ __launch_bounds__(256) void f32_to_bf16_vec(
    const float* __restrict__ in, unsigned short* __restrict__ out) {
  long i = (long)blockIdx.x * 256 + threadIdx.x;   // element-of-4 index
  float4 v = reinterpret_cast<const float4*>(in)[i];
  ushort4 o;
  o.x = f2b(v.x); o.y = f2b(v.y); o.z = f2b(v.z); o.w = f2b(v.w);
  reinterpret_cast<ushort4*>(out)[i] = o;
}

// Bt1: (1024 x 768). Row j<512: cos(2*pi*j*n/768); row j>=512: sin(2*pi*(j-512)*n/768).
__global__ __launch_bounds__(256) void fill_bt1(unsigned short* __restrict__ Bt1) {
  int i = blockIdx.x * 256 + threadIdx.x;          // < 1024*768
  int j = i / 768;
  int n = i - j * 768;
  int jj = j & 511;
  int m = (jj * n) % 768;
  float ang = (float)m * (6.283185307179586f / 768.0f);
  Bt1[i] = f2b((j < 512) ? cosf(ang) : sinf(ang));
}

// Au[k][s] = cos(2*pi*k*s/4096), Av[k][s] = sin(...), k=0..2303 (padded), s=0..4095.
__global__ __launch_bounds__(256) void fill_auv(
    unsigned short* __restrict__ Au, unsigned short* __restrict__ Av) {
  long i = (long)blockIdx.x * 256 + threadIdx.x;   // < 2304*4096
  int k = (int)(i >> 12);
  int s = (int)(i & 4095);
  int mm = (k * s) & 4095;
  float ang = (float)mm * (6.283185307179586f / 4096.0f);
  Au[i] = f2b(cosf(ang));
  Av[i] = f2b(sinf(ang));
}

// out[c][r] = bf16(in[r][c]); R,C multiples of 32  (for W1, W2)
__global__ __launch_bounds__(256) void transpose_f32_to_bf16(
    const float* __restrict__ in, unsigned short* __restrict__ out, int R, int C) {
  __shared__ float tile[32][33];
  const int c0 = blockIdx.x * 32;
  const int r0 = blockIdx.y * 32;
  const int tx = threadIdx.x & 31;
  const int ty = threadIdx.x >> 5;   // 0..7
#pragma unroll
  for (int i = ty; i < 32; i += 8)
    tile[i][tx] = in[(long)(r0 + i) * C + c0 + tx];
  __syncthreads();
#pragma unroll
  for (int i = ty; i < 32; i += 8)
    out[(long)(c0 + i) * R + r0 + tx] = f2b(tile[tx][i]);
}

// BtUV[(d<512?0:HALF) + (b*512 + (d&511))*4096 + s] = T[(b*4096+s)*1024 + d]
__global__ __launch_bounds__(256) void transpose_T(
    const unsigned short* __restrict__ T, unsigned short* __restrict__ BtUV) {
  __shared__ unsigned short tile[32][33];
  const int s0 = blockIdx.x * 32;
  const int d0 = blockIdx.y * 32;
  const int b  = blockIdx.z;
  const int tx = threadIdx.x & 31;
  const int ty = threadIdx.x >> 5;   // 0..7
  const unsigned short* Tb = T + ((long)b * 4096 + s0) * 1024 + d0;
#pragma unroll
  for (int i = ty; i < 32; i += 8)
    tile[i][tx] = Tb[(long)i * 1024 + tx];       // tile[s_local][d_local]
  __syncthreads();
#pragma unroll
  for (int i = ty; i < 32; i += 8) {
    const int d = d0 + i;
    const long off = (d < 512) ? 0L : 16777216L;
    BtUV[off + ((long)b * 512 + (d & 511)) * 4096 + s0 + tx] = tile[tx][i];
  }
}

// ---------------------------------------------------------------------------
// GEMM256: C = A (MxK row-major bf16) @ Bt^T (Bt NxK row-major bf16)
// 256x256 tile, BK=64, 512 threads (8 waves, 2x4), per-wave 128x64 output.
// LDS: 2 x (A 32KB + B 32KB) = 128 KiB double-buffer.
// Pipeline: 2-deep prefetch, counted vmcnt(8), raw barriers.
// T2 swizzle: LDS byte ^= (row&7)<<4 on reads; inverse pre-applied to the
// per-lane GLOBAL source column in staging (gload_lds dest stays linear).
// Epilogues: 0 = bf16 store (GEMM1->T); 1 = fp32 z-batched store, z>=zSplit
//            switches to (A2p,Bt2p,outF2) operand set (fused GEMM_u/GEMM_v);
//            2 = +bias, exact gelu, bf16 (GEMM3->H); 3 = +bias+bf16resid, fp32.
// M,N multiples of 256; K multiple of 64; K/64 >= 2.
// ---------------------------------------------------------------------------

template <int EPI>
__global__ __launch_bounds__(512, 2) void gemm256(
    const unsigned short* __restrict__ A, const unsigned short* __restrict__ Bt,
    const unsigned short* __restrict__ A2p, const unsigned short* __restrict__ Bt2p,
    int K, int lda, int ldb, long bBatch, long oBatch, int zSplit,
    float* __restrict__ outF, float* __restrict__ outF2,
    unsigned short* __restrict__ outB,
    const float* __restrict__ bias, const unsigned short* __restrict__ residB,
    int ldOut) {
  __shared__ __align__(16) unsigned short AsB[2][16384];   // [buf][256 rows][64 cols]
  __shared__ __align__(16) unsigned short BsB[2][16384];

  const int tid = threadIdx.x;
  const int lane = tid & 63;
  const int wid = tid >> 6;          // 0..7
  const int wm = wid >> 2;           // 0..1
  const int wn = wid & 3;            // 0..3

  int zz = blockIdx.z;
  const unsigned short* Ax = A;
  const unsigned short* Bx = Bt;
  float* oF = outF;
  if (EPI == 1 && zz >= zSplit) { Ax = A2p; Bx = Bt2p; oF = outF2; zz -= zSplit; }

  const unsigned short* Ab = Ax + (long)blockIdx.x * 256 * lda;
  const unsigned short* Bb = Bx + (long)zz * bBatch + (long)blockIdx.y * 256 * ldb;

  const int NT = K >> 6;             // number of BK=64 tiles (>= 2)

  // --- staging: one call = 8 gload_lds instrs/wave (4 A + 4 B), 64 KB total ---
  const int srow = (lane >> 3);                       // 0..7  (row within 8-row region)
  const int scolE = ((lane & 7) ^ (lane >> 3)) << 3;  // pre-swizzled source col (elems)
#define STAGE(buf, kt) do {                                                            \
    const unsigned short* As_ = Ab + (long)(kt) * 64;                                  \
    const unsigned short* Bs_ = Bb + (long)(kt) * 64;                                  \
    _Pragma("unroll")                                                                  \
    for (int i_ = 0; i_ < 4; ++i_) {                                                   \
      const int R_ = i_ * 8 + wid;                   /* region 0..31, wave-uniform */  \
      const int row_ = R_ * 8 + srow;                                                  \
      __builtin_amdgcn_global_load_lds(                                                \
        (const __attribute__((address_space(1))) void*)(As_ + (long)row_ * lda + scolE), \
        (__attribute__((address_space(3))) void*)(&AsB[buf][R_ * 512]), 16, 0, 0);     \
      __builtin_amdgcn_global_load_lds(                                                \
        (const __attribute__((address_space(1))) void*)(Bs_ + (long)row_ * ldb + scolE), \
        (__attribute__((address_space(3))) void*)(&BsB[buf][R_ * 512]), 16, 0, 0);     \
    } } while (0)

  // --- swizzled fragment reads (row&7 == lane&7 for all frag rows) ---
  const int fr = lane & 15;          // frag row within 16
  const int fkE = (lane >> 4) << 3;  // k-offset elems (0,8,16,24)
  const int fxor = (lane & 7) << 4;  // T2 swizzle XOR (lane-constant)

  f32x4 acc[8][4] = {};

  STAGE(0, 0);
  STAGE(1, 1);
  asm volatile("s_waitcnt vmcnt(8)" ::: "memory");
  __builtin_amdgcn_sched_barrier(0);
  __builtin_amdgcn_s_barrier();
  __builtin_amdgcn_sched_barrier(0);

  for (int t = 0; t < NT; ++t) {
    const int cur = t & 1;
    const char* Ap = reinterpret_cast<const char*>(&AsB[cur][0]);
    const char* Bp = reinterpret_cast<const char*>(&BsB[cur][0]);

    short8 bq[8];
#pragma unroll
    for (int nf = 0; nf < 4; ++nf)
#pragma unroll
      for (int ks = 0; ks < 2; ++ks) {
        const int row = wn * 64 + nf * 16 + fr;
        const int byte = ((row * 64 + ks * 32 + fkE) * 2) ^ fxor;
        bq[nf * 2 + ks] = *reinterpret_cast<const short8*>(Bp + byte);
      }
#pragma unroll
    for (int mh = 0; mh < 2; ++mh) {
      short8 aq[8];
#pragma unroll
      for (int mf = 0; mf < 4; ++mf)
#pragma unroll
        for (int ks = 0; ks < 2; ++ks) {
          const int row = wm * 128 + (mh * 4 + mf) * 16 + fr;
          const int byte = ((row * 64 + ks * 32 + fkE) * 2) ^ fxor;
          aq[mf * 2 + ks] = *reinterpret_cast<const short8*>(Ap + byte);
        }
      __builtin_amdgcn_s_setprio(1);
#pragma unroll
      for (int mf = 0; mf < 4; ++mf)
#pragma unroll
        for (int nf = 0; nf < 4; ++nf)
#pragma unroll
          for (int ks = 0; ks < 2; ++ks)
            acc[mh * 4 + mf][nf] = __builtin_amdgcn_mfma_f32_16x16x32_bf16(
                aq[mf * 2 + ks], bq[nf * 2 + ks], acc[mh * 4 + mf][nf], 0, 0, 0);
      __builtin_amdgcn_s_setprio(0);
    }

    if (t + 1 < NT) {
      __builtin_amdgcn_sched_barrier(0);
      __builtin_amdgcn_s_barrier();            // all waves done reading buf[cur]
      if (t + 2 < NT) {
        STAGE(cur, t + 2);                     // refill freed buffer
        asm volatile("s_waitcnt vmcnt(8)" ::: "memory");   // tile t+1 landed
      } else {
        asm volatile("s_waitcnt vmcnt(0)" ::: "memory");   // final drain (once)
      }
      __builtin_amdgcn_sched_barrier(0);
      __builtin_amdgcn_s_barrier();            // buf[cur^1] visible to all waves
      __builtin_amdgcn_sched_barrier(0);
    }
  }
#undef STAGE

  // Epilogue. C/D layout: col = lane&15, row = (lane>>4)*4 + reg  [m89/m91]
  const long rowBase = (long)blockIdx.x * 256 + wm * 128 + ((lane >> 4) << 2);
  const int colBase = (int)blockIdx.y * 256 + wn * 64 + (lane & 15);
#pragma unroll
  for (int mf = 0; mf < 8; ++mf) {
#pragma unroll
    for (int nf = 0; nf < 4; ++nf) {
      const int col = colBase + nf * 16;
#pragma unroll
      for (int i = 0; i < 4; ++i) {
        const long r = rowBase + mf * 16 + i;
        float vv = acc[mf][nf][i];
        if constexpr (EPI == 0) {
          outB[r * (long)ldOut + col] = f2b(vv);
        } else if constexpr (EPI == 1) {
          oF[(long)zz * oBatch + r * (long)ldOut + col] = vv;
        } else if constexpr (EPI == 2) {
          float tt = vv + bias[col];
          float g = 0.5f * tt * (1.0f + erff(tt * 0.7071067811865476f));
          outB[r * (long)ldOut + col] = f2b(g);
        } else {
          const long idx = r * (long)ldOut + col;
          outF[idx] = vv + bias[col] + b2f(residB[idx]);
        }
      }
    }
  }
}

// ---------------------------------------------------------------------------
// Quadrant combine: y1 = attn + x, each output written exactly once.
// ---------------------------------------------------------------------------
__global__ __launch_bounds__(256) void combine_quadrants(
    const float* __restrict__ u, const float* __restrict__ v,
    const float* __restrict__ x, float* __restrict__ y) {
  const int k = blockIdx.x;            // 0..2048
  const int z = blockIdx.y;            // 0..7
  const long ub = ((long)z * 2304 + k) * 512;
  const long base = (long)z * 4096 * 768;
  const long rowA = base + (long)k * 768;
  const long rowB = base + (long)(4096 - k) * 768;
  const bool doRowB = (k != 0) && (k != 2048);
  for (int d = threadIdx.x; d <= 384; d += 256) {
    const float uu = u[ub + d];
    const float vv = v[ub + d];
    const float a1 = uu - vv;
    const float a2 = uu + vv;
    const int dd = 768 - d;
    const bool doColB = (d != 0) && (d != 384);
    y[rowA + d] = a1 + x[rowA + d];
    if (doColB) y[rowA + dd] = a2 + x[rowA + dd];
    if (doRowB) {
      y[rowB + d] = a2 + x[rowB + d];
      if (doColB) y[rowB + dd] = a1 + x[rowB + dd];
    }
  }
}

// ---------------------------------------------------------------------------
// Row LayerNorm over D=768. One 256-thread block per row, 3 elems/thread.
// ---------------------------------------------------------------------------
template <int MODE>
__global__ __launch_bounds__(256) void ln_row(
    const float* __restrict__ in, const float* __restrict__ gamma,
    const float* __restrict__ beta, unsigned short* __restrict__ outB,
    float* __restrict__ outF) {
  const long row = blockIdx.x;
  const float* p = in + row * 768;
  const int t = threadIdx.x;
  const float v0 = p[t], v1 = p[t + 256], v2 = p[t + 512];
  float s = v0 + v1 + v2;
  float q = v0 * v0 + v1 * v1 + v2 * v2;
#pragma unroll
  for (int off = 32; off > 0; off >>= 1) {
    s += __shfl_down(s, off, 64);
    q += __shfl_down(q, off, 64);
  }
  __shared__ float ss[4], sq[4];
  if ((t & 63) == 0) { ss[t >> 6] = s; sq[t >> 6] = q; }
  __syncthreads();
  const float S = ss[0] + ss[1] + ss[2] + ss[3];
  const float Q = sq[0] + sq[1] + sq[2] + sq[3];
  const float mu = S * (1.0f / 768.0f);
  const float var = Q * (1.0f / 768.0f) - mu * mu;
  const float rs = rsqrtf(var + 1e-6f);
  const float o0 = (v0 - mu) * rs * gamma[t] + beta[t];
  const float o1 = (v1 - mu) * rs * gamma[t + 256] + beta[t + 256];
  const float o2 = (v2 - mu) * rs * gamma[t + 512] + beta[t + 512];
  if constexpr (MODE == 0) {
    outB[row * 768 + t] = f2b(o0);
    outB[row * 768 + t + 256] = f2b(o1);
    outB[row * 768 + t + 512] = f2b(o2);
  } else {
    outF[row * 768 + t] = o0;
    outF[row * 768 + t + 256] = o1;
    outF[row * 768 + t + 512] = o2;
  }
}

// ---------------------------------------------------------------------------

extern "C" void kernel_launch(void* const* d_in, const int* in_sizes, int n_in,
                              void* d_out, int out_size, void* d_ws, size_t ws_size,
                              hipStream_t stream) {
  const float* x   = (const float*)d_in[0];   // (8,4096,768)
  const float* W1  = (const float*)d_in[1];   // (768,3072)
  const float* b1  = (const float*)d_in[2];   // (3072)
  const float* W2  = (const float*)d_in[3];   // (3072,768)
  const float* b2  = (const float*)d_in[4];   // (768)
  const float* g1  = (const float*)d_in[5];
  const float* be1 = (const float*)d_in[6];
  const float* g2  = (const float*)d_in[7];
  const float* be2 = (const float*)d_in[8];
  float* out = (float*)d_out;                 // fp32, also y1/y2 scratch

  char* ws = (char*)d_ws;
  unsigned short* xb   = (unsigned short*)(ws + 0L);           //  50,331,648
  unsigned short* Bt1  = (unsigned short*)(ws + 50331648L);    //   1,572,864
  unsigned short* Au   = (unsigned short*)(ws + 51904512L);    //  18,874,368
  unsigned short* Av   = (unsigned short*)(ws + 70778880L);    //  18,874,368
  unsigned short* T    = (unsigned short*)(ws + 89653248L);    //  67,108,864 -> ends 156,762,112
  unsigned short* BtUV = (unsigned short*)(ws + 156762112L);   //  67,108,864 -> ends 223,870,976
  float*          u    = (float*)        (ws + 0L);            //  37,748,736 (aliases xb; dead after GEMM1)
  float*          v    = (float*)        (ws + 89653248L);     //  37,748,736 (aliases T; dead after transpose_T)
  unsigned short* H    = (unsigned short*)(ws + 0L);           // 201,326,592 (aliases all FFT buffers, dead by GEMM3)
  unsigned short* o1b  = (unsigned short*)(ws + 201326592L);   //  50,331,648 (overlaps BtUV tail, dead by LN1)
  unsigned short* W1t  = (unsigned short*)(ws + 251658240L);   //   4,718,592
  unsigned short* W2t  = (unsigned short*)(ws + 256376832L);   //   4,718,592
  // total ws needed: 261,095,424 bytes (~249 MiB)

  // --- prep ---
  f32_to_bf16_vec<<<24576, 256, 0, stream>>>(x, xb);
  fill_bt1<<<3072, 256, 0, stream>>>(Bt1);
  fill_auv<<<36864, 256, 0, stream>>>(Au, Av);                 // 2304*4096/256
  transpose_f32_to_bf16<<<dim3(96, 24), 256, 0, stream>>>(W1, W1t, 768, 3072);
  transpose_f32_to_bf16<<<dim3(24, 96), 256, 0, stream>>>(W2, W2t, 3072, 768);

  // --- GEMM1: T = xb @ Bt1^T (row-major, ld 1024) ---
  gemm256<0><<<dim3(128, 4, 1), 512, 0, stream>>>(
      xb, Bt1, nullptr, nullptr, 768, 768, 768, 0L, 0L, 999,
      nullptr, nullptr, T, nullptr, nullptr, 1024);

  // --- transpose T -> BtU/BtV ([b][d][s]) ---
  transpose_T<<<dim3(128, 32, 8), 256, 0, stream>>>(T, BtUV);

  // --- GEMM_uv fused (z<8: u = C_S @ Tc; z>=8: v = S_S @ Ts) ---
  gemm256<1><<<dim3(9, 2, 16), 512, 0, stream>>>(
      Au, BtUV, Av, BtUV + 16777216L, 4096, 4096, 4096,
      512L * 4096L, 2304L * 512L, 8,
      u, v, nullptr, nullptr, nullptr, 512);

  // --- combine quadrants + x residual -> y1 (d_out) ---
  combine_quadrants<<<dim3(2049, 8), 256, 0, stream>>>(u, v, x, out);

  // --- LN1 -> out1 (bf16) ---
  ln_row<0><<<32768, 256, 0, stream>>>(out, g1, be1, o1b, nullptr);

  // --- GEMM3: H = gelu(out1 @ W1 + b1) ---
  gemm256<2><<<dim3(128, 12, 1), 512, 0, stream>>>(
      o1b, W1t, nullptr, nullptr, 768, 768, 768, 0L, 0L, 999,
      nullptr, nullptr, H, b1, nullptr, 3072);

  // --- GEMM4: y2 = H @ W2 + b2 + out1 -> d_out ---
  gemm256<3><<<dim3(128, 3, 1), 512, 0, stream>>>(
      H, W2t, nullptr, nullptr, 3072, 3072, 3072, 0L, 0L, 999,
      out, nullptr, nullptr, b2, o1b, 768);

  // --- LN2 in-place ---
  ln_row<1><<<32768, 256, 0, stream>>>(out, g2, be2, nullptr, out);
}